// Round 8
// baseline (509.481 us; speedup 1.0000x reference)
//
#include <hip/hip_runtime.h>
#include <hip/hip_bf16.h>

#define TD 128   // feature dim, fixed by problem
#define XS 136   // padded X-tile row stride in bf16 (+8 keeps b128 align, breaks bank conflicts)
#define SC_T 8   // triples per scoring block

typedef __attribute__((ext_vector_type(8))) short bf16x8;   // 8 bf16 = 4 VGPR (MFMA A/B frag)
typedef __attribute__((ext_vector_type(4))) float f32x4;    // MFMA C/D frag

static __device__ __forceinline__ unsigned short f2bf(float f) {
    unsigned int u = __float_as_uint(f);
    u += 0x7fffu + ((u >> 16) & 1u);   // round-to-nearest-even
    return (unsigned short)(u >> 16);
}
static __device__ __forceinline__ float bf2f(unsigned short h) {
    return __uint_as_float((unsigned int)h << 16);
}

// ---------------- pass 1: degree + within-bucket rank (single atomic pass) ----------------
__global__ __launch_bounds__(256) void k_rank(const int* __restrict__ ei, int* __restrict__ deg,
                                              int* __restrict__ rank, int E_) {
    int e = blockIdx.x * 256 + threadIdx.x;
    if (e < E_) rank[e] = atomicAdd(&deg[ei[E_ + e]], 1);   // dst = row 1
}

__global__ __launch_bounds__(256) void k_dinv(const int* __restrict__ deg, float* __restrict__ dinv, int n) {
    int i = blockIdx.x * 256 + threadIdx.x;
    if (i < n) {
        int d = deg[i];
        dinv[i] = (d > 0) ? 1.0f / sqrtf((float)d) : 0.0f;
    }
}

// ---------------- exclusive scan (3-kernel hierarchical) ----------------
__global__ __launch_bounds__(256) void k_scan1(const int* __restrict__ deg, int* __restrict__ rowptr,
                                               int* __restrict__ bsums, int n) {
    __shared__ int wsum[4];
    int t = threadIdx.x;
    int base = blockIdx.x * 1024 + t * 4;
    int a0 = 0, a1 = 0, a2 = 0, a3 = 0;
    if (base + 3 < n) {
        int4 v = *(const int4*)(deg + base);
        a0 = v.x; a1 = v.y; a2 = v.z; a3 = v.w;
    } else {
        if (base     < n) a0 = deg[base];
        if (base + 1 < n) a1 = deg[base + 1];
        if (base + 2 < n) a2 = deg[base + 2];
        if (base + 3 < n) a3 = deg[base + 3];
    }
    int s1 = a0 + a1, s2 = s1 + a2, tot = s2 + a3;
    int lane = t & 63, wv = t >> 6;
    int x = tot;
#pragma unroll
    for (int off = 1; off < 64; off <<= 1) {
        int y = __shfl_up(x, off);
        if (lane >= off) x += y;
    }
    if (lane == 63) wsum[wv] = x;
    __syncthreads();
    int woff = 0;
    for (int w = 0; w < wv; ++w) woff += wsum[w];
    int excl = woff + x - tot;
    if (base     < n) rowptr[base]     = excl;
    if (base + 1 < n) rowptr[base + 1] = excl + a0;
    if (base + 2 < n) rowptr[base + 2] = excl + s1;
    if (base + 3 < n) rowptr[base + 3] = excl + s2;
    if (t == 255) bsums[blockIdx.x] = woff + x;   // block total
}

// parallel single-block scan of block sums (nb <= 1024)
__global__ __launch_bounds__(256) void k_scan2(int* __restrict__ bsums, int nb, int* __restrict__ rowptrN) {
    __shared__ int wsum[4];
    int t = threadIdx.x;
    int base = t * 4;
    int a0 = (base     < nb) ? bsums[base]     : 0;
    int a1 = (base + 1 < nb) ? bsums[base + 1] : 0;
    int a2 = (base + 2 < nb) ? bsums[base + 2] : 0;
    int a3 = (base + 3 < nb) ? bsums[base + 3] : 0;
    int s1 = a0 + a1, s2 = s1 + a2, tot = s2 + a3;
    int lane = t & 63, wv = t >> 6;
    int x = tot;
#pragma unroll
    for (int off = 1; off < 64; off <<= 1) {
        int y = __shfl_up(x, off);
        if (lane >= off) x += y;
    }
    if (lane == 63) wsum[wv] = x;
    __syncthreads();
    int woff = 0;
    for (int w = 0; w < wv; ++w) woff += wsum[w];
    int excl = woff + x - tot;
    if (base     < nb) bsums[base]     = excl;
    if (base + 1 < nb) bsums[base + 1] = excl + a0;
    if (base + 2 < nb) bsums[base + 2] = excl + s1;
    if (base + 3 < nb) bsums[base + 3] = excl + s2;
    if (t == 255) *rowptrN = woff + x;   // grand total = E
}

__global__ __launch_bounds__(256) void k_scan3(int* __restrict__ rowptr, const int* __restrict__ bsums, int n) {
    int i = blockIdx.x * 256 + threadIdx.x;
    if (i < n) rowptr[i] += bsums[i >> 10];
}

// ---------------- pass 2: atomic-free placement ----------------
__global__ __launch_bounds__(256) void k_place(const int* __restrict__ ei, const int* __restrict__ rowptr,
                                               const int* __restrict__ rank, int* __restrict__ esrc, int E_) {
    int e = blockIdx.x * 256 + threadIdx.x;
    if (e < E_) {
        int s = ei[e];
        int d = ei[E_ + e];
        esrc[rowptr[d] + rank[e]] = s;
    }
}

// ---------------- W transpose + hi/lo bf16 split ----------------
__global__ __launch_bounds__(256) void k_wsplit(const float* __restrict__ W1, const float* __restrict__ W2,
                                                unsigned short* __restrict__ Wt) {
    int i = blockIdx.x * 256 + threadIdx.x;   // 0 .. 2*16384-1
    int w = i >> 14;
    int idx = i & 16383;          // = k*128 + n  (coalesced read)
    int k = idx >> 7, n = idx & 127;
    float x = (w ? W2 : W1)[idx];
    unsigned short h = f2bf(x);
    unsigned short l = f2bf(x - bf2f(h));
    size_t base = (size_t)w * 32768;
    Wt[base + n * 128 + k] = h;
    Wt[base + 16384 + n * 128 + k] = l;
}

// ---------------- MFMA GEMM: out[r][c] = bf16(scale[r] * sum_k X[r][k]*W[k][c]) ----------------
// f32-equivalent precision via bf16 hi/lo split: A*B ~= Ah*Bh + Al*Bh + Ah*Bl  (rel err ~2^-18).
// v3: 64-row tile, 1 m-tile (16 rows) per wave. LDS 34.8 KB -> 4 blocks/CU; launch_bounds(256,4)
// caps VGPR at 128 -> 16 waves/CU (4x R7's occupancy) to hide W-load (L2 ~200cyc) + ds_read latency.
__global__ __launch_bounds__(256, 4) void k_gemm(const float* __restrict__ X,
                                                 const unsigned short* __restrict__ Wth,
                                                 const unsigned short* __restrict__ Wtl,
                                                 const float* __restrict__ scale,
                                                 unsigned short* __restrict__ out,
                                                 int nrows) {
    __shared__ __align__(16) unsigned short Xh[64 * XS];   // 17.4 KB (reused as C-stage)
    __shared__ __align__(16) unsigned short Xl[64 * XS];   // 17.4 KB
    const int t = threadIdx.x;
    const int w = t >> 6;
    const int lane = t & 63;
    const int l15 = lane & 15;
    const int quad = lane >> 4;
    const int m0 = w * 16;
    const int rbase = blockIdx.x * 64;

    // stage 64 rows x 128 f32 -> bf16 hi/lo: 2048 float4 over 256 thr = 8 iters
#pragma unroll
    for (int it = 0; it < 8; ++it) {
        int idx = t + it * 256;
        int row = idx >> 5, c4 = idx & 31;
        int gr = rbase + row;
        float4 v = make_float4(0.f, 0.f, 0.f, 0.f);
        if (gr < nrows) v = ((const float4*)(X + (size_t)gr * TD))[c4];
        unsigned short h0 = f2bf(v.x), h1 = f2bf(v.y), h2 = f2bf(v.z), h3 = f2bf(v.w);
        ushort4 hh, ll;
        hh.x = h0; hh.y = h1; hh.z = h2; hh.w = h3;
        ll.x = f2bf(v.x - bf2f(h0)); ll.y = f2bf(v.y - bf2f(h1));
        ll.z = f2bf(v.z - bf2f(h2)); ll.w = f2bf(v.w - bf2f(h3));
        *(ushort4*)&Xh[row * XS + c4 * 4] = hh;
        *(ushort4*)&Xl[row * XS + c4 * 4] = ll;
    }
    __syncthreads();

    f32x4 acc[8];
#pragma unroll
    for (int b = 0; b < 8; ++b) acc[b] = (f32x4){0.f, 0.f, 0.f, 0.f};

#pragma unroll
    for (int kc = 0; kc < 4; ++kc) {
        const int koff = kc * 32 + quad * 8;
        bf16x8 ah = *(const bf16x8*)&Xh[(m0 + l15) * XS + koff];
        bf16x8 al = *(const bf16x8*)&Xl[(m0 + l15) * XS + koff];
#pragma unroll
        for (int b = 0; b < 8; ++b) {
            const size_t boff = (size_t)(b * 16 + l15) * 128 + koff;
            bf16x8 bh = *(const bf16x8*)&Wth[boff];
            bf16x8 bl = *(const bf16x8*)&Wtl[boff];
            acc[b] = __builtin_amdgcn_mfma_f32_16x16x32_bf16(ah, bh, acc[b], 0, 0, 0);
            acc[b] = __builtin_amdgcn_mfma_f32_16x16x32_bf16(al, bh, acc[b], 0, 0, 0);
            acc[b] = __builtin_amdgcn_mfma_f32_16x16x32_bf16(ah, bl, acc[b], 0, 0, 0);
        }
    }
    __syncthreads();   // all X reads done; Xh becomes C-stage

    // epilogue: C/D layout col=lane&15, row=quad*4+reg -> scale, bf16, stage to LDS
    {
        int lrow = m0 + quad * 4;                 // multiple of 4
        int grow = rbase + lrow;
        float4 s4 = make_float4(0.f, 0.f, 0.f, 0.f);
        if (grow < nrows) s4 = *(const float4*)&scale[grow];   // nrows % 4 == 0
#pragma unroll
        for (int b = 0; b < 8; ++b) {
            int col = b * 16 + l15;
            Xh[(lrow + 0) * XS + col] = f2bf(acc[b][0] * s4.x);
            Xh[(lrow + 1) * XS + col] = f2bf(acc[b][1] * s4.y);
            Xh[(lrow + 2) * XS + col] = f2bf(acc[b][2] * s4.z);
            Xh[(lrow + 3) * XS + col] = f2bf(acc[b][3] * s4.w);
        }
    }
    __syncthreads();

    // coalesced copy-out: 4 rounds x (16 rows x 256 B)
#pragma unroll
    for (int rr = 0; rr < 4; ++rr) {
        int row = rr * 16 + (t >> 4);
        int gr = rbase + row;
        if (gr < nrows) {
            uint4 v = *(const uint4*)&Xh[row * XS + (t & 15) * 8];
            *(uint4*)(out + (size_t)gr * TD + (t & 15) * 8) = v;
        }
    }
}

// ---------------- CSR aggregation: bf16 gather, f64 accumulate (order-invariant), f32 out ----------------
__global__ __launch_bounds__(256) void k_agg(const unsigned short* __restrict__ hs, const int* __restrict__ rowptr,
                                             const int* __restrict__ esrc, const float* __restrict__ dinv,
                                             const float* __restrict__ bias, float* __restrict__ out,
                                             int n, int relu) {
    int node = blockIdx.x * 16 + (threadIdx.x >> 4);
    int lane = threadIdx.x & 15;
    if (node >= n) return;
    int s = rowptr[node], e = rowptr[node + 1];
    const uint4* h16 = (const uint4*)hs;
    double a0 = 0, a1 = 0, a2 = 0, a3 = 0, a4 = 0, a5 = 0, a6 = 0, a7 = 0;
    int i = s;
    for (; i + 2 <= e; i += 2) {
        uint4 u = h16[(size_t)esrc[i] * 16 + lane];
        uint4 v = h16[(size_t)esrc[i + 1] * 16 + lane];
        a0 += (double)__uint_as_float(u.x << 16); a1 += (double)__uint_as_float(u.x & 0xffff0000u);
        a2 += (double)__uint_as_float(u.y << 16); a3 += (double)__uint_as_float(u.y & 0xffff0000u);
        a4 += (double)__uint_as_float(u.z << 16); a5 += (double)__uint_as_float(u.z & 0xffff0000u);
        a6 += (double)__uint_as_float(u.w << 16); a7 += (double)__uint_as_float(u.w & 0xffff0000u);
        a0 += (double)__uint_as_float(v.x << 16); a1 += (double)__uint_as_float(v.x & 0xffff0000u);
        a2 += (double)__uint_as_float(v.y << 16); a3 += (double)__uint_as_float(v.y & 0xffff0000u);
        a4 += (double)__uint_as_float(v.z << 16); a5 += (double)__uint_as_float(v.z & 0xffff0000u);
        a6 += (double)__uint_as_float(v.w << 16); a7 += (double)__uint_as_float(v.w & 0xffff0000u);
    }
    if (i < e) {
        uint4 u = h16[(size_t)esrc[i] * 16 + lane];
        a0 += (double)__uint_as_float(u.x << 16); a1 += (double)__uint_as_float(u.x & 0xffff0000u);
        a2 += (double)__uint_as_float(u.y << 16); a3 += (double)__uint_as_float(u.y & 0xffff0000u);
        a4 += (double)__uint_as_float(u.z << 16); a5 += (double)__uint_as_float(u.z & 0xffff0000u);
        a6 += (double)__uint_as_float(u.w << 16); a7 += (double)__uint_as_float(u.w & 0xffff0000u);
    }
    double di = (double)dinv[node];
    float4 b0 = ((const float4*)bias)[lane * 2];
    float4 b1 = ((const float4*)bias)[lane * 2 + 1];
    float o0 = (float)(di * a0 + (double)b0.x);
    float o1 = (float)(di * a1 + (double)b0.y);
    float o2 = (float)(di * a2 + (double)b0.z);
    float o3 = (float)(di * a3 + (double)b0.w);
    float o4 = (float)(di * a4 + (double)b1.x);
    float o5 = (float)(di * a5 + (double)b1.y);
    float o6 = (float)(di * a6 + (double)b1.z);
    float o7 = (float)(di * a7 + (double)b1.w);
    if (relu) {
        o0 = fmaxf(o0, 0.f); o1 = fmaxf(o1, 0.f); o2 = fmaxf(o2, 0.f); o3 = fmaxf(o3, 0.f);
        o4 = fmaxf(o4, 0.f); o5 = fmaxf(o5, 0.f); o6 = fmaxf(o6, 0.f); o7 = fmaxf(o7, 0.f);
    }
    ((float4*)out)[(size_t)node * 32 + lane * 2]     = make_float4(o0, o1, o2, o3);
    ((float4*)out)[(size_t)node * 32 + lane * 2 + 1] = make_float4(o4, o5, o6, o7);
}

// ---------------- relation bucketing: block-aggregated histograms (16 global atomics/block) ----------------
__global__ __launch_bounds__(256) void k_rcnt(const int* __restrict__ rel, int* __restrict__ rcount, int es) {
    __shared__ int lh[16];
    int t = threadIdx.x;
    if (t < 16) lh[t] = 0;
    __syncthreads();
#pragma unroll
    for (int i = 0; i < 4; ++i) {
        int e = blockIdx.x * 1024 + i * 256 + t;
        if (e < es) atomicAdd(&lh[rel[e]], 1);
    }
    __syncthreads();
    if (t < 16 && lh[t]) atomicAdd(&rcount[t], lh[t]);
}

__global__ void k_roff(const int* __restrict__ rcount, int* __restrict__ roff,
                       int* __restrict__ chunkoff, int nr) {
    if (threadIdx.x == 0 && blockIdx.x == 0) {
        int run = 0, crun = 0;
        for (int r = 0; r < nr; ++r) {
            roff[r] = run; chunkoff[r] = crun;
            run += rcount[r]; crun += (rcount[r] + SC_T - 1) / SC_T;
        }
        roff[nr] = run; chunkoff[nr] = crun;
    }
}

__global__ __launch_bounds__(256) void k_bucket(const int* __restrict__ rel, int* __restrict__ cursor,
                                                int* __restrict__ eidx, int es) {
    __shared__ int lh[16];
    __shared__ int lbase[16];
    int t = threadIdx.x;
    if (t < 16) lh[t] = 0;
    __syncthreads();
    int r[4], lr[4];
#pragma unroll
    for (int i = 0; i < 4; ++i) {
        int e = blockIdx.x * 1024 + i * 256 + t;
        if (e < es) {
            r[i] = rel[e];
            lr[i] = atomicAdd(&lh[r[i]], 1);   // LDS atomic: intra-block rank
        } else r[i] = -1;
    }
    __syncthreads();
    if (t < 16) lbase[t] = lh[t] ? atomicAdd(&cursor[t], lh[t]) : 0;   // reserve range
    __syncthreads();
#pragma unroll
    for (int i = 0; i < 4; ++i)
        if (r[i] >= 0) eidx[lbase[r[i]] + lr[i]] = blockIdx.x * 1024 + i * 256 + t;
}

// ---------------- batched scoring: SC_T triples of ONE relation per block, W[r] staged once ----------------
__global__ __launch_bounds__(256) void k_score_r(const float* __restrict__ z, const float* __restrict__ relW,
                                                 const int* __restrict__ eidx, const int* __restrict__ head,
                                                 const int* __restrict__ tail, const int* __restrict__ roff,
                                                 const int* __restrict__ chunkoff, float* __restrict__ out,
                                                 int R_) {
    __shared__ __align__(16) float Wl[TD * TD];      // 64 KB
    __shared__ __align__(16) float zhL[SC_T * TD];   // 4 KB
    __shared__ __align__(16) float ztL[SC_T * TD];   // 4 KB
    __shared__ int eids[SC_T];
    __shared__ int co[17], ro[17];
    __shared__ float red[4][SC_T];
    const int t = threadIdx.x;
    const int b = blockIdx.x;
    if (t < 17 && t <= R_) { co[t] = chunkoff[t]; ro[t] = roff[t]; }
    __syncthreads();
    int r = 0;
    while (r < R_ && co[r + 1] <= b) ++r;
    if (r >= R_) return;                       // uniform: all threads exit together
    const int base = ro[r] + (b - co[r]) * SC_T;
    const int nt = min(SC_T, ro[r + 1] - base);
    if (t < SC_T) eids[t] = (t < nt) ? eidx[base + t] : -1;
    __syncthreads();
    {   // stage zh/zt: 256 float4, 1 per thread
        int tt = t >> 5, c4 = t & 31;
        float4 vh = make_float4(0.f, 0.f, 0.f, 0.f), vt = vh;
        int e = eids[tt];
        if (e >= 0) {
            vh = ((const float4*)(z + (size_t)head[e] * TD))[c4];
            vt = ((const float4*)(z + (size_t)tail[e] * TD))[c4];
        }
        ((float4*)(zhL + tt * TD))[c4] = vh;
        ((float4*)(ztL + tt * TD))[c4] = vt;
    }
    {   // stage W[r]: 4096 float4
        const float4* W4 = (const float4*)(relW + (size_t)r * TD * TD);
        float4* Wl4 = (float4*)Wl;
#pragma unroll
        for (int i = 0; i < 16; ++i) Wl4[t + i * 256] = W4[t + i * 256];
    }
    __syncthreads();

    const int c  = (t & 31) * 4;    // cols c..c+3
    const int i0 = (t >> 5) * 16;   // 16-row i segment
    float4 acc[SC_T];
#pragma unroll
    for (int u = 0; u < SC_T; ++u) acc[u] = make_float4(0.f, 0.f, 0.f, 0.f);
#pragma unroll 4
    for (int i = i0; i < i0 + 16; ++i) {
        float4 wv = *(const float4*)&Wl[i * TD + c];
#pragma unroll
        for (int u = 0; u < SC_T; ++u) {
            float h = zhL[u * TD + i];
            acc[u].x = fmaf(h, wv.x, acc[u].x);
            acc[u].y = fmaf(h, wv.y, acc[u].y);
            acc[u].z = fmaf(h, wv.z, acc[u].z);
            acc[u].w = fmaf(h, wv.w, acc[u].w);
        }
    }
    float pth[SC_T];
#pragma unroll
    for (int u = 0; u < SC_T; ++u) {
        float4 z4 = *(const float4*)&ztL[u * TD + c];
        pth[u] = acc[u].x * z4.x + acc[u].y * z4.y + acc[u].z * z4.z + acc[u].w * z4.w;
    }
#pragma unroll
    for (int off = 32; off > 0; off >>= 1)
#pragma unroll
        for (int u = 0; u < SC_T; ++u) pth[u] += __shfl_down(pth[u], off);
    if ((t & 63) == 0) {
        int wv = t >> 6;
#pragma unroll
        for (int u = 0; u < SC_T; ++u) red[wv][u] = pth[u];
    }
    __syncthreads();
    if (t < SC_T) {
        int e = eids[t];
        if (e >= 0) out[e] = red[0][t] + red[1][t] + red[2][t] + red[3][t];
    }
}

extern "C" void kernel_launch(void* const* d_in, const int* in_sizes, int n_in,
                              void* d_out, int out_size, void* d_ws, size_t ws_size,
                              hipStream_t stream) {
    const float* x0   = (const float*)d_in[0];
    const float* W1   = (const float*)d_in[1];
    const float* b1   = (const float*)d_in[2];
    const float* W2   = (const float*)d_in[3];
    const float* b2   = (const float*)d_in[4];
    const float* relW = (const float*)d_in[5];
    const int*   ei   = (const int*)d_in[6];
    const int*   rel  = (const int*)d_in[7];
    const int*   head = (const int*)d_in[8];
    const int*   tail = (const int*)d_in[9];
    float* outp = (float*)d_out;

    const int N_  = in_sizes[0] / TD;
    const int E_  = in_sizes[6] / 2;
    const int ES_ = in_sizes[7];
    const int R_  = in_sizes[5] / (TD * TD);
    const int nb  = (N_ + 1023) / 1024;
    const int ntiles64 = (N_ + 63) / 64;

    char* p = (char*)d_ws;
    auto alloc = [&](size_t bytes) { char* r = p; p += (bytes + 255) & ~(size_t)255; return r; };
    int*            deg    = (int*)           alloc((size_t)N_ * 4);
    float*          dinv   = (float*)         alloc((size_t)N_ * 4);
    int*            rowptr = (int*)           alloc(((size_t)N_ + 1) * 4);
    int*            bsums  = (int*)           alloc((size_t)nb * 4);
    int*            esrc   = (int*)           alloc((size_t)E_ * 4);
    unsigned short* Wt     = (unsigned short*)alloc((size_t)4 * 16384 * 2);   // W1h,W1l,W2h,W2l
    int*            rcount = (int*)           alloc((size_t)R_ * 4);
    int*            roff   = (int*)           alloc(((size_t)R_ + 1) * 4);
    int*            chkoff = (int*)           alloc(((size_t)R_ + 1) * 4);
    int*            cursor = (int*)           alloc((size_t)R_ * 4);
    int*            eidx   = (int*)           alloc((size_t)ES_ * 4);
    unsigned short* bufA   = (unsigned short*)alloc((size_t)N_ * TD * 2);     // bf16 h-scaled
    float*          bufB   = (float*)         alloc((size_t)N_ * TD * 4);     // f32 conv out
    int*            rank   = (int*)bufA;   // alias: dead before first k_gemm writes bufA (E*4 <= N*TD*2)

    hipMemsetAsync(deg, 0, (size_t)N_ * 4, stream);
    hipMemsetAsync(rcount, 0, (size_t)R_ * 4, stream);
    k_rank  <<<(E_ + 255) / 256, 256, 0, stream>>>(ei, deg, rank, E_);
    k_dinv  <<<(N_ + 255) / 256, 256, 0, stream>>>(deg, dinv, N_);
    k_scan1 <<<nb, 256, 0, stream>>>(deg, rowptr, bsums, N_);
    k_scan2 <<<1, 256, 0, stream>>>(bsums, nb, rowptr + N_);
    k_scan3 <<<(N_ + 255) / 256, 256, 0, stream>>>(rowptr, bsums, N_);
    k_place <<<(E_ + 255) / 256, 256, 0, stream>>>(ei, rowptr, rank, esrc, E_);
    k_wsplit<<<128, 256, 0, stream>>>(W1, W2, Wt);

    // relation bucketing for scoring (block-aggregated atomics)
    k_rcnt  <<<(ES_ + 1023) / 1024, 256, 0, stream>>>(rel, rcount, ES_);
    k_roff  <<<1, 64, 0, stream>>>(rcount, roff, chkoff, R_);
    hipMemcpyAsync(cursor, roff, (size_t)R_ * 4, hipMemcpyDeviceToDevice, stream);
    k_bucket<<<(ES_ + 1023) / 1024, 256, 0, stream>>>(rel, cursor, eidx, ES_);

    // conv1: bufA = bf16(dinv * (x0 @ W1)); bufB = relu(dinv*agg(bufA) + b1)
    k_gemm<<<ntiles64, 256, 0, stream>>>(x0, Wt, Wt + 16384, dinv, bufA, N_);
    k_agg <<<(N_ + 15) / 16, 256, 0, stream>>>(bufA, rowptr, esrc, dinv, b1, bufB, N_, 1);
    // conv2: bufA = bf16(dinv * (bufB @ W2)); bufB = dinv*agg(bufA) + b2  (= z)
    k_gemm<<<ntiles64, 256, 0, stream>>>(bufB, Wt + 32768, Wt + 49152, dinv, bufA, N_);
    k_agg <<<(N_ + 15) / 16, 256, 0, stream>>>(bufA, rowptr, esrc, dinv, b2, bufB, N_, 0);

    // scoring: blocks = chunks (upper bound ES/SC_T + R); out-of-range blocks exit via chunkoff
    k_score_r<<<(ES_ + SC_T - 1) / SC_T + R_, 256, 0, stream>>>(bufB, relW, eidx, head, tail,
                                                                roff, chkoff, outp, R_);
}

// Round 10
// 501.131 us; speedup vs baseline: 1.0167x; 1.0167x over previous
//
#include <hip/hip_runtime.h>
#include <hip/hip_bf16.h>

#define TD 128   // feature dim, fixed by problem
#define XS 136   // padded C-stage row stride in bf16
#define SC_T 8   // triples per scoring block

typedef __attribute__((ext_vector_type(8))) short bf16x8;   // 8 bf16 = 4 VGPR (MFMA A/B frag)
typedef __attribute__((ext_vector_type(4))) float f32x4;    // MFMA C/D frag

static __device__ __forceinline__ unsigned short f2bf(float f) {
    unsigned int u = __float_as_uint(f);
    u += 0x7fffu + ((u >> 16) & 1u);   // round-to-nearest-even
    return (unsigned short)(u >> 16);
}
static __device__ __forceinline__ float bf2f(unsigned short h) {
    return __uint_as_float((unsigned int)h << 16);
}

// ---------------- pass 1: degree + within-bucket rank (single atomic pass) ----------------
__global__ __launch_bounds__(256) void k_rank(const int* __restrict__ ei, int* __restrict__ deg,
                                              int* __restrict__ rank, int E_) {
    int e = blockIdx.x * 256 + threadIdx.x;
    if (e < E_) rank[e] = atomicAdd(&deg[ei[E_ + e]], 1);   // dst = row 1
}

__global__ __launch_bounds__(256) void k_dinv(const int* __restrict__ deg, float* __restrict__ dinv, int n) {
    int i = blockIdx.x * 256 + threadIdx.x;
    if (i < n) {
        int d = deg[i];
        dinv[i] = (d > 0) ? 1.0f / sqrtf((float)d) : 0.0f;
    }
}

// ---------------- exclusive scan (3-kernel hierarchical) ----------------
__global__ __launch_bounds__(256) void k_scan1(const int* __restrict__ deg, int* __restrict__ rowptr,
                                               int* __restrict__ bsums, int n) {
    __shared__ int wsum[4];
    int t = threadIdx.x;
    int base = blockIdx.x * 1024 + t * 4;
    int a0 = 0, a1 = 0, a2 = 0, a3 = 0;
    if (base + 3 < n) {
        int4 v = *(const int4*)(deg + base);
        a0 = v.x; a1 = v.y; a2 = v.z; a3 = v.w;
    } else {
        if (base     < n) a0 = deg[base];
        if (base + 1 < n) a1 = deg[base + 1];
        if (base + 2 < n) a2 = deg[base + 2];
        if (base + 3 < n) a3 = deg[base + 3];
    }
    int s1 = a0 + a1, s2 = s1 + a2, tot = s2 + a3;
    int lane = t & 63, wv = t >> 6;
    int x = tot;
#pragma unroll
    for (int off = 1; off < 64; off <<= 1) {
        int y = __shfl_up(x, off);
        if (lane >= off) x += y;
    }
    if (lane == 63) wsum[wv] = x;
    __syncthreads();
    int woff = 0;
    for (int w = 0; w < wv; ++w) woff += wsum[w];
    int excl = woff + x - tot;
    if (base     < n) rowptr[base]     = excl;
    if (base + 1 < n) rowptr[base + 1] = excl + a0;
    if (base + 2 < n) rowptr[base + 2] = excl + s1;
    if (base + 3 < n) rowptr[base + 3] = excl + s2;
    if (t == 255) bsums[blockIdx.x] = woff + x;   // block total
}

// parallel single-block scan of block sums (nb <= 1024)
__global__ __launch_bounds__(256) void k_scan2(int* __restrict__ bsums, int nb, int* __restrict__ rowptrN) {
    __shared__ int wsum[4];
    int t = threadIdx.x;
    int base = t * 4;
    int a0 = (base     < nb) ? bsums[base]     : 0;
    int a1 = (base + 1 < nb) ? bsums[base + 1] : 0;
    int a2 = (base + 2 < nb) ? bsums[base + 2] : 0;
    int a3 = (base + 3 < nb) ? bsums[base + 3] : 0;
    int s1 = a0 + a1, s2 = s1 + a2, tot = s2 + a3;
    int lane = t & 63, wv = t >> 6;
    int x = tot;
#pragma unroll
    for (int off = 1; off < 64; off <<= 1) {
        int y = __shfl_up(x, off);
        if (lane >= off) x += y;
    }
    if (lane == 63) wsum[wv] = x;
    __syncthreads();
    int woff = 0;
    for (int w = 0; w < wv; ++w) woff += wsum[w];
    int excl = woff + x - tot;
    if (base     < nb) bsums[base]     = excl;
    if (base + 1 < nb) bsums[base + 1] = excl + a0;
    if (base + 2 < nb) bsums[base + 2] = excl + s1;
    if (base + 3 < nb) bsums[base + 3] = excl + s2;
    if (t == 255) *rowptrN = woff + x;   // grand total = E
}

__global__ __launch_bounds__(256) void k_scan3(int* __restrict__ rowptr, const int* __restrict__ bsums, int n) {
    int i = blockIdx.x * 256 + threadIdx.x;
    if (i < n) rowptr[i] += bsums[i >> 10];
}

// ---------------- pass 2: atomic-free placement ----------------
__global__ __launch_bounds__(256) void k_place(const int* __restrict__ ei, const int* __restrict__ rowptr,
                                               const int* __restrict__ rank, int* __restrict__ esrc, int E_) {
    int e = blockIdx.x * 256 + threadIdx.x;
    if (e < E_) {
        int s = ei[e];
        int d = ei[E_ + e];
        esrc[rowptr[d] + rank[e]] = s;
    }
}

// ---------------- W transpose + hi/lo bf16 split ----------------
__global__ __launch_bounds__(256) void k_wsplit(const float* __restrict__ W1, const float* __restrict__ W2,
                                                unsigned short* __restrict__ Wt) {
    int i = blockIdx.x * 256 + threadIdx.x;   // 0 .. 2*16384-1
    int w = i >> 14;
    int idx = i & 16383;          // = k*128 + n  (coalesced read)
    int k = idx >> 7, n = idx & 127;
    float x = (w ? W2 : W1)[idx];
    unsigned short h = f2bf(x);
    unsigned short l = f2bf(x - bf2f(h));
    size_t base = (size_t)w * 32768;
    Wt[base + n * 128 + k] = h;
    Wt[base + 16384 + n * 128 + k] = l;
}

// ---------------- MFMA GEMM v4.1: barrier-free, A-frags direct from global ----------------
// out[r][c] = bf16(scale[r] * sum_k X[r][k]*W[k][c]); f32-equiv precision via bf16 hi/lo split.
// Each lane loads its OWN A data (row = lane&15 of the wave's 16-row tile, 8 f32 per kc),
// converts to bf16 hi/lo in registers -> no LDS staging, no __syncthreads at all.
// W frags from L2-resident pre-transposed Wt. Epilogue: per-wave private LDS C-stage
// (same-wave DS ops execute in order), then wave-local coalesced bf16 store.
// R9 bug fixed: copy-out now covers all 128 columns (16 col-groups x 4 rows x 4 rounds).
__global__ __launch_bounds__(256, 4) void k_gemm(const float* __restrict__ X,
                                                 const unsigned short* __restrict__ Wth,
                                                 const unsigned short* __restrict__ Wtl,
                                                 const float* __restrict__ scale,
                                                 unsigned short* __restrict__ out,
                                                 int nrows) {
    __shared__ __align__(16) unsigned short Cst[4][16 * XS];   // 17.4 KB, per-wave private
    const int t = threadIdx.x;
    const int w = t >> 6;
    const int lane = t & 63;
    const int l15 = lane & 15;
    const int quad = lane >> 4;
    const int rbase = blockIdx.x * 64 + w * 16;   // wave's 16-row tile
    const int arow = rbase + l15;                 // this lane's A row
    const bool avalid = arow < nrows;

    // A: 8 float4 loads (independent, issue immediately; 16 rows x full lines per instr)
    float4 xa[4][2];
#pragma unroll
    for (int kc = 0; kc < 4; ++kc) {
        const float* src = X + (size_t)arow * TD + kc * 32 + quad * 8;
        xa[kc][0] = avalid ? *(const float4*)src       : make_float4(0.f, 0.f, 0.f, 0.f);
        xa[kc][1] = avalid ? *(const float4*)(src + 4) : make_float4(0.f, 0.f, 0.f, 0.f);
    }
    // convert to bf16 hi/lo A-fragments (frag j = X[row][kc*32 + quad*8 + j])
    bf16x8 ah[4], al[4];
#pragma unroll
    for (int kc = 0; kc < 4; ++kc) {
#pragma unroll
        for (int j = 0; j < 8; ++j) {
            float v = (j < 4) ? ((const float*)&xa[kc][0])[j] : ((const float*)&xa[kc][1])[j - 4];
            unsigned short h = f2bf(v);
            ah[kc][j] = (short)h;
            al[kc][j] = (short)f2bf(v - bf2f(h));
        }
    }

    f32x4 acc[8];
#pragma unroll
    for (int b = 0; b < 8; ++b) acc[b] = (f32x4){0.f, 0.f, 0.f, 0.f};

#pragma unroll
    for (int kc = 0; kc < 4; ++kc) {
        const int koff = kc * 32 + quad * 8;
#pragma unroll
        for (int b = 0; b < 8; ++b) {
            const size_t boff = (size_t)(b * 16 + l15) * 128 + koff;
            bf16x8 bh = *(const bf16x8*)&Wth[boff];
            bf16x8 bl = *(const bf16x8*)&Wtl[boff];
            acc[b] = __builtin_amdgcn_mfma_f32_16x16x32_bf16(ah[kc], bh, acc[b], 0, 0, 0);
            acc[b] = __builtin_amdgcn_mfma_f32_16x16x32_bf16(al[kc], bh, acc[b], 0, 0, 0);
            acc[b] = __builtin_amdgcn_mfma_f32_16x16x32_bf16(ah[kc], bl, acc[b], 0, 0, 0);
        }
    }

    // epilogue: C/D layout col=lane&15, row=quad*4+reg -> scale, bf16, per-wave LDS stage
    unsigned short* cs = Cst[w];
    {
        int lrow = quad * 4;                      // local row of reg 0 within wave tile
        int grow = rbase + lrow;
        float4 s4 = make_float4(0.f, 0.f, 0.f, 0.f);
        if (grow < nrows) s4 = *(const float4*)&scale[grow];   // nrows % 4 == 0
#pragma unroll
        for (int b = 0; b < 8; ++b) {
            int col = b * 16 + l15;
            cs[(lrow + 0) * XS + col] = f2bf(acc[b][0] * s4.x);
            cs[(lrow + 1) * XS + col] = f2bf(acc[b][1] * s4.y);
            cs[(lrow + 2) * XS + col] = f2bf(acc[b][2] * s4.z);
            cs[(lrow + 3) * XS + col] = f2bf(acc[b][3] * s4.w);
        }
    }
    // wave-local coalesced copy-out: 4 rounds x (4 rows x 16 col-groups) = 16 rows x 128 cols
#pragma unroll
    for (int rr = 0; rr < 4; ++rr) {
        int lr = rr * 4 + (lane >> 4);
        int gr = rbase + lr;
        if (gr < nrows) {
            uint4 v = *(const uint4*)&cs[lr * XS + (lane & 15) * 8];
            *(uint4*)(out + (size_t)gr * TD + (lane & 15) * 8) = v;
        }
    }
}

// ---------------- CSR aggregation: bf16 gather, f64 accumulate (order-invariant), f32 out ----------------
__global__ __launch_bounds__(256) void k_agg(const unsigned short* __restrict__ hs, const int* __restrict__ rowptr,
                                             const int* __restrict__ esrc, const float* __restrict__ dinv,
                                             const float* __restrict__ bias, float* __restrict__ out,
                                             int n, int relu) {
    int node = blockIdx.x * 16 + (threadIdx.x >> 4);
    int lane = threadIdx.x & 15;
    if (node >= n) return;
    int s = rowptr[node], e = rowptr[node + 1];
    const uint4* h16 = (const uint4*)hs;
    double a0 = 0, a1 = 0, a2 = 0, a3 = 0, a4 = 0, a5 = 0, a6 = 0, a7 = 0;
    int i = s;
    for (; i + 2 <= e; i += 2) {
        uint4 u = h16[(size_t)esrc[i] * 16 + lane];
        uint4 v = h16[(size_t)esrc[i + 1] * 16 + lane];
        a0 += (double)__uint_as_float(u.x << 16); a1 += (double)__uint_as_float(u.x & 0xffff0000u);
        a2 += (double)__uint_as_float(u.y << 16); a3 += (double)__uint_as_float(u.y & 0xffff0000u);
        a4 += (double)__uint_as_float(u.z << 16); a5 += (double)__uint_as_float(u.z & 0xffff0000u);
        a6 += (double)__uint_as_float(u.w << 16); a7 += (double)__uint_as_float(u.w & 0xffff0000u);
        a0 += (double)__uint_as_float(v.x << 16); a1 += (double)__uint_as_float(v.x & 0xffff0000u);
        a2 += (double)__uint_as_float(v.y << 16); a3 += (double)__uint_as_float(v.y & 0xffff0000u);
        a4 += (double)__uint_as_float(v.z << 16); a5 += (double)__uint_as_float(v.z & 0xffff0000u);
        a6 += (double)__uint_as_float(v.w << 16); a7 += (double)__uint_as_float(v.w & 0xffff0000u);
    }
    if (i < e) {
        uint4 u = h16[(size_t)esrc[i] * 16 + lane];
        a0 += (double)__uint_as_float(u.x << 16); a1 += (double)__uint_as_float(u.x & 0xffff0000u);
        a2 += (double)__uint_as_float(u.y << 16); a3 += (double)__uint_as_float(u.y & 0xffff0000u);
        a4 += (double)__uint_as_float(u.z << 16); a5 += (double)__uint_as_float(u.z & 0xffff0000u);
        a6 += (double)__uint_as_float(u.w << 16); a7 += (double)__uint_as_float(u.w & 0xffff0000u);
    }
    double di = (double)dinv[node];
    float4 b0 = ((const float4*)bias)[lane * 2];
    float4 b1 = ((const float4*)bias)[lane * 2 + 1];
    float o0 = (float)(di * a0 + (double)b0.x);
    float o1 = (float)(di * a1 + (double)b0.y);
    float o2 = (float)(di * a2 + (double)b0.z);
    float o3 = (float)(di * a3 + (double)b0.w);
    float o4 = (float)(di * a4 + (double)b1.x);
    float o5 = (float)(di * a5 + (double)b1.y);
    float o6 = (float)(di * a6 + (double)b1.z);
    float o7 = (float)(di * a7 + (double)b1.w);
    if (relu) {
        o0 = fmaxf(o0, 0.f); o1 = fmaxf(o1, 0.f); o2 = fmaxf(o2, 0.f); o3 = fmaxf(o3, 0.f);
        o4 = fmaxf(o4, 0.f); o5 = fmaxf(o5, 0.f); o6 = fmaxf(o6, 0.f); o7 = fmaxf(o7, 0.f);
    }
    ((float4*)out)[(size_t)node * 32 + lane * 2]     = make_float4(o0, o1, o2, o3);
    ((float4*)out)[(size_t)node * 32 + lane * 2 + 1] = make_float4(o4, o5, o6, o7);
}

// ---------------- relation bucketing: block-aggregated histograms (16 global atomics/block) ----------------
__global__ __launch_bounds__(256) void k_rcnt(const int* __restrict__ rel, int* __restrict__ rcount, int es) {
    __shared__ int lh[16];
    int t = threadIdx.x;
    if (t < 16) lh[t] = 0;
    __syncthreads();
#pragma unroll
    for (int i = 0; i < 4; ++i) {
        int e = blockIdx.x * 1024 + i * 256 + t;
        if (e < es) atomicAdd(&lh[rel[e]], 1);
    }
    __syncthreads();
    if (t < 16 && lh[t]) atomicAdd(&rcount[t], lh[t]);
}

__global__ void k_roff(const int* __restrict__ rcount, int* __restrict__ roff,
                       int* __restrict__ chunkoff, int nr) {
    if (threadIdx.x == 0 && blockIdx.x == 0) {
        int run = 0, crun = 0;
        for (int r = 0; r < nr; ++r) {
            roff[r] = run; chunkoff[r] = crun;
            run += rcount[r]; crun += (rcount[r] + SC_T - 1) / SC_T;
        }
        roff[nr] = run; chunkoff[nr] = crun;
    }
}

__global__ __launch_bounds__(256) void k_bucket(const int* __restrict__ rel, int* __restrict__ cursor,
                                                int* __restrict__ eidx, int es) {
    __shared__ int lh[16];
    __shared__ int lbase[16];
    int t = threadIdx.x;
    if (t < 16) lh[t] = 0;
    __syncthreads();
    int r[4], lr[4];
#pragma unroll
    for (int i = 0; i < 4; ++i) {
        int e = blockIdx.x * 1024 + i * 256 + t;
        if (e < es) {
            r[i] = rel[e];
            lr[i] = atomicAdd(&lh[r[i]], 1);   // LDS atomic: intra-block rank
        } else r[i] = -1;
    }
    __syncthreads();
    if (t < 16) lbase[t] = lh[t] ? atomicAdd(&cursor[t], lh[t]) : 0;   // reserve range
    __syncthreads();
#pragma unroll
    for (int i = 0; i < 4; ++i)
        if (r[i] >= 0) eidx[lbase[r[i]] + lr[i]] = blockIdx.x * 1024 + i * 256 + t;
}

// ---------------- batched scoring: SC_T triples of ONE relation per block, W[r] staged once ----------------
__global__ __launch_bounds__(256) void k_score_r(const float* __restrict__ z, const float* __restrict__ relW,
                                                 const int* __restrict__ eidx, const int* __restrict__ head,
                                                 const int* __restrict__ tail, const int* __restrict__ roff,
                                                 const int* __restrict__ chunkoff, float* __restrict__ out,
                                                 int R_) {
    __shared__ __align__(16) float Wl[TD * TD];      // 64 KB
    __shared__ __align__(16) float zhL[SC_T * TD];   // 4 KB
    __shared__ __align__(16) float ztL[SC_T * TD];   // 4 KB
    __shared__ int eids[SC_T];
    __shared__ int co[17], ro[17];
    __shared__ float red[4][SC_T];
    const int t = threadIdx.x;
    const int b = blockIdx.x;
    if (t < 17 && t <= R_) { co[t] = chunkoff[t]; ro[t] = roff[t]; }
    __syncthreads();
    int r = 0;
    while (r < R_ && co[r + 1] <= b) ++r;
    if (r >= R_) return;                       // uniform: all threads exit together
    const int base = ro[r] + (b - co[r]) * SC_T;
    const int nt = min(SC_T, ro[r + 1] - base);
    if (t < SC_T) eids[t] = (t < nt) ? eidx[base + t] : -1;
    __syncthreads();
    {   // stage zh/zt: 256 float4, 1 per thread
        int tt = t >> 5, c4 = t & 31;
        float4 vh = make_float4(0.f, 0.f, 0.f, 0.f), vt = vh;
        int e = eids[tt];
        if (e >= 0) {
            vh = ((const float4*)(z + (size_t)head[e] * TD))[c4];
            vt = ((const float4*)(z + (size_t)tail[e] * TD))[c4];
        }
        ((float4*)(zhL + tt * TD))[c4] = vh;
        ((float4*)(ztL + tt * TD))[c4] = vt;
    }
    {   // stage W[r]: 4096 float4
        const float4* W4 = (const float4*)(relW + (size_t)r * TD * TD);
        float4* Wl4 = (float4*)Wl;
#pragma unroll
        for (int i = 0; i < 16; ++i) Wl4[t + i * 256] = W4[t + i * 256];
    }
    __syncthreads();

    const int c  = (t & 31) * 4;    // cols c..c+3
    const int i0 = (t >> 5) * 16;   // 16-row i segment
    float4 acc[SC_T];
#pragma unroll
    for (int u = 0; u < SC_T; ++u) acc[u] = make_float4(0.f, 0.f, 0.f, 0.f);
#pragma unroll 4
    for (int i = i0; i < i0 + 16; ++i) {
        float4 wv = *(const float4*)&Wl[i * TD + c];
#pragma unroll
        for (int u = 0; u < SC_T; ++u) {
            float h = zhL[u * TD + i];
            acc[u].x = fmaf(h, wv.x, acc[u].x);
            acc[u].y = fmaf(h, wv.y, acc[u].y);
            acc[u].z = fmaf(h, wv.z, acc[u].z);
            acc[u].w = fmaf(h, wv.w, acc[u].w);
        }
    }
    float pth[SC_T];
#pragma unroll
    for (int u = 0; u < SC_T; ++u) {
        float4 z4 = *(const float4*)&ztL[u * TD + c];
        pth[u] = acc[u].x * z4.x + acc[u].y * z4.y + acc[u].z * z4.z + acc[u].w * z4.w;
    }
#pragma unroll
    for (int off = 32; off > 0; off >>= 1)
#pragma unroll
        for (int u = 0; u < SC_T; ++u) pth[u] += __shfl_down(pth[u], off);
    if ((t & 63) == 0) {
        int wv = t >> 6;
#pragma unroll
        for (int u = 0; u < SC_T; ++u) red[wv][u] = pth[u];
    }
    __syncthreads();
    if (t < SC_T) {
        int e = eids[t];
        if (e >= 0) out[e] = red[0][t] + red[1][t] + red[2][t] + red[3][t];
    }
}

extern "C" void kernel_launch(void* const* d_in, const int* in_sizes, int n_in,
                              void* d_out, int out_size, void* d_ws, size_t ws_size,
                              hipStream_t stream) {
    const float* x0   = (const float*)d_in[0];
    const float* W1   = (const float*)d_in[1];
    const float* b1   = (const float*)d_in[2];
    const float* W2   = (const float*)d_in[3];
    const float* b2   = (const float*)d_in[4];
    const float* relW = (const float*)d_in[5];
    const int*   ei   = (const int*)d_in[6];
    const int*   rel  = (const int*)d_in[7];
    const int*   head = (const int*)d_in[8];
    const int*   tail = (const int*)d_in[9];
    float* outp = (float*)d_out;

    const int N_  = in_sizes[0] / TD;
    const int E_  = in_sizes[6] / 2;
    const int ES_ = in_sizes[7];
    const int R_  = in_sizes[5] / (TD * TD);
    const int nb  = (N_ + 1023) / 1024;
    const int ntiles64 = (N_ + 63) / 64;

    char* p = (char*)d_ws;
    auto alloc = [&](size_t bytes) { char* r = p; p += (bytes + 255) & ~(size_t)255; return r; };
    int*            deg    = (int*)           alloc((size_t)N_ * 4);
    float*          dinv   = (float*)         alloc((size_t)N_ * 4);
    int*            rowptr = (int*)           alloc(((size_t)N_ + 1) * 4);
    int*            bsums  = (int*)           alloc((size_t)nb * 4);
    int*            esrc   = (int*)           alloc((size_t)E_ * 4);
    unsigned short* Wt     = (unsigned short*)alloc((size_t)4 * 16384 * 2);   // W1h,W1l,W2h,W2l
    int*            rcount = (int*)           alloc((size_t)R_ * 4);
    int*            roff   = (int*)           alloc(((size_t)R_ + 1) * 4);
    int*            chkoff = (int*)           alloc(((size_t)R_ + 1) * 4);
    int*            cursor = (int*)           alloc((size_t)R_ * 4);
    int*            eidx   = (int*)           alloc((size_t)ES_ * 4);
    unsigned short* bufA   = (unsigned short*)alloc((size_t)N_ * TD * 2);     // bf16 h-scaled
    float*          bufB   = (float*)         alloc((size_t)N_ * TD * 4);     // f32 conv out
    int*            rank   = (int*)bufA;   // alias: dead before first k_gemm writes bufA (E*4 <= N*TD*2)

    hipMemsetAsync(deg, 0, (size_t)N_ * 4, stream);
    hipMemsetAsync(rcount, 0, (size_t)R_ * 4, stream);
    k_rank  <<<(E_ + 255) / 256, 256, 0, stream>>>(ei, deg, rank, E_);
    k_dinv  <<<(N_ + 255) / 256, 256, 0, stream>>>(deg, dinv, N_);
    k_scan1 <<<nb, 256, 0, stream>>>(deg, rowptr, bsums, N_);
    k_scan2 <<<1, 256, 0, stream>>>(bsums, nb, rowptr + N_);
    k_scan3 <<<(N_ + 255) / 256, 256, 0, stream>>>(rowptr, bsums, N_);
    k_place <<<(E_ + 255) / 256, 256, 0, stream>>>(ei, rowptr, rank, esrc, E_);
    k_wsplit<<<128, 256, 0, stream>>>(W1, W2, Wt);

    // relation bucketing for scoring (block-aggregated atomics)
    k_rcnt  <<<(ES_ + 1023) / 1024, 256, 0, stream>>>(rel, rcount, ES_);
    k_roff  <<<1, 64, 0, stream>>>(rcount, roff, chkoff, R_);
    hipMemcpyAsync(cursor, roff, (size_t)R_ * 4, hipMemcpyDeviceToDevice, stream);
    k_bucket<<<(ES_ + 1023) / 1024, 256, 0, stream>>>(rel, cursor, eidx, ES_);

    // conv1: bufA = bf16(dinv * (x0 @ W1)); bufB = relu(dinv*agg(bufA) + b1)
    k_gemm<<<ntiles64, 256, 0, stream>>>(x0, Wt, Wt + 16384, dinv, bufA, N_);
    k_agg <<<(N_ + 15) / 16, 256, 0, stream>>>(bufA, rowptr, esrc, dinv, b1, bufB, N_, 1);
    // conv2: bufA = bf16(dinv * (bufB @ W2)); bufB = dinv*agg(bufA) + b2  (= z)
    k_gemm<<<ntiles64, 256, 0, stream>>>(bufB, Wt + 32768, Wt + 49152, dinv, bufA, N_);
    k_agg <<<(N_ + 15) / 16, 256, 0, stream>>>(bufA, rowptr, esrc, dinv, b2, bufB, N_, 0);

    // scoring: blocks = chunks (upper bound ES/SC_T + R); out-of-range blocks exit via chunkoff
    k_score_r<<<(ES_ + SC_T - 1) / SC_T + R_, 256, 0, stream>>>(bufB, relW, eidx, head, tail,
                                                                roff, chkoff, outp, R_);
}

// Round 11
// 421.598 us; speedup vs baseline: 1.2084x; 1.1886x over previous
//
#include <hip/hip_runtime.h>
#include <hip/hip_bf16.h>

#define TD 128   // feature dim, fixed by problem
#define WS 136   // padded W-LDS row stride in bf16 (272 B: 16B-aligned, bank-uniform for b128)
#define SC_T 8   // triples per scoring block

typedef __attribute__((ext_vector_type(8))) short bf16x8;   // 8 bf16 = 4 VGPR (MFMA A/B frag)
typedef __attribute__((ext_vector_type(4))) float f32x4;    // MFMA C/D frag

static __device__ __forceinline__ unsigned short f2bf(float f) {
    unsigned int u = __float_as_uint(f);
    u += 0x7fffu + ((u >> 16) & 1u);   // round-to-nearest-even
    return (unsigned short)(u >> 16);
}
static __device__ __forceinline__ float bf2f(unsigned short h) {
    return __uint_as_float((unsigned int)h << 16);
}

// ---------------- pass 1: degree + within-bucket rank (single atomic pass) ----------------
__global__ __launch_bounds__(256) void k_rank(const int* __restrict__ ei, int* __restrict__ deg,
                                              int* __restrict__ rank, int E_) {
    int e = blockIdx.x * 256 + threadIdx.x;
    if (e < E_) rank[e] = atomicAdd(&deg[ei[E_ + e]], 1);   // dst = row 1
}

__global__ __launch_bounds__(256) void k_dinv(const int* __restrict__ deg, float* __restrict__ dinv, int n) {
    int i = blockIdx.x * 256 + threadIdx.x;
    if (i < n) {
        int d = deg[i];
        dinv[i] = (d > 0) ? 1.0f / sqrtf((float)d) : 0.0f;
    }
}

// ---------------- exclusive scan (3-kernel hierarchical) ----------------
__global__ __launch_bounds__(256) void k_scan1(const int* __restrict__ deg, int* __restrict__ rowptr,
                                               int* __restrict__ bsums, int n) {
    __shared__ int wsum[4];
    int t = threadIdx.x;
    int base = blockIdx.x * 1024 + t * 4;
    int a0 = 0, a1 = 0, a2 = 0, a3 = 0;
    if (base + 3 < n) {
        int4 v = *(const int4*)(deg + base);
        a0 = v.x; a1 = v.y; a2 = v.z; a3 = v.w;
    } else {
        if (base     < n) a0 = deg[base];
        if (base + 1 < n) a1 = deg[base + 1];
        if (base + 2 < n) a2 = deg[base + 2];
        if (base + 3 < n) a3 = deg[base + 3];
    }
    int s1 = a0 + a1, s2 = s1 + a2, tot = s2 + a3;
    int lane = t & 63, wv = t >> 6;
    int x = tot;
#pragma unroll
    for (int off = 1; off < 64; off <<= 1) {
        int y = __shfl_up(x, off);
        if (lane >= off) x += y;
    }
    if (lane == 63) wsum[wv] = x;
    __syncthreads();
    int woff = 0;
    for (int w = 0; w < wv; ++w) woff += wsum[w];
    int excl = woff + x - tot;
    if (base     < n) rowptr[base]     = excl;
    if (base + 1 < n) rowptr[base + 1] = excl + a0;
    if (base + 2 < n) rowptr[base + 2] = excl + s1;
    if (base + 3 < n) rowptr[base + 3] = excl + s2;
    if (t == 255) bsums[blockIdx.x] = woff + x;   // block total
}

// parallel single-block scan of block sums (nb <= 1024)
__global__ __launch_bounds__(256) void k_scan2(int* __restrict__ bsums, int nb, int* __restrict__ rowptrN) {
    __shared__ int wsum[4];
    int t = threadIdx.x;
    int base = t * 4;
    int a0 = (base     < nb) ? bsums[base]     : 0;
    int a1 = (base + 1 < nb) ? bsums[base + 1] : 0;
    int a2 = (base + 2 < nb) ? bsums[base + 2] : 0;
    int a3 = (base + 3 < nb) ? bsums[base + 3] : 0;
    int s1 = a0 + a1, s2 = s1 + a2, tot = s2 + a3;
    int lane = t & 63, wv = t >> 6;
    int x = tot;
#pragma unroll
    for (int off = 1; off < 64; off <<= 1) {
        int y = __shfl_up(x, off);
        if (lane >= off) x += y;
    }
    if (lane == 63) wsum[wv] = x;
    __syncthreads();
    int woff = 0;
    for (int w = 0; w < wv; ++w) woff += wsum[w];
    int excl = woff + x - tot;
    if (base     < nb) bsums[base]     = excl;
    if (base + 1 < nb) bsums[base + 1] = excl + a0;
    if (base + 2 < nb) bsums[base + 2] = excl + s1;
    if (base + 3 < nb) bsums[base + 3] = excl + s2;
    if (t == 255) *rowptrN = woff + x;   // grand total = E
}

__global__ __launch_bounds__(256) void k_scan3(int* __restrict__ rowptr, const int* __restrict__ bsums, int n) {
    int i = blockIdx.x * 256 + threadIdx.x;
    if (i < n) rowptr[i] += bsums[i >> 10];
}

// ---------------- pass 2: atomic-free placement ----------------
__global__ __launch_bounds__(256) void k_place(const int* __restrict__ ei, const int* __restrict__ rowptr,
                                               const int* __restrict__ rank, int* __restrict__ esrc, int E_) {
    int e = blockIdx.x * 256 + threadIdx.x;
    if (e < E_) {
        int s = ei[e];
        int d = ei[E_ + e];
        esrc[rowptr[d] + rank[e]] = s;
    }
}

// ---------------- W transpose + hi/lo bf16 split ----------------
__global__ __launch_bounds__(256) void k_wsplit(const float* __restrict__ W1, const float* __restrict__ W2,
                                                unsigned short* __restrict__ Wt) {
    int i = blockIdx.x * 256 + threadIdx.x;   // 0 .. 2*16384-1
    int w = i >> 14;
    int idx = i & 16383;          // = k*128 + n  (coalesced read)
    int k = idx >> 7, n = idx & 127;
    float x = (w ? W2 : W1)[idx];
    unsigned short h = f2bf(x);
    unsigned short l = f2bf(x - bf2f(h));
    size_t base = (size_t)w * 32768;
    Wt[base + n * 128 + k] = h;
    Wt[base + 16384 + n * 128 + k] = l;
}

// ---------------- MFMA GEMM v5: W hi+lo staged to LDS once per block ----------------
// out[r][c] = bf16(scale[r] * sum_k X[r][k]*W[k][c]); f32-equiv precision via bf16 hi/lo split
// (A*B ~= Ah*Bh + Al*Bh + Ah*Bl). R7-R10 all plateaued ~70us: every wave re-read 64KB of W
// via global loads that serialize at L2 latency (vmcnt(0) per pair at low VGPR). Fix: W lives
// in LDS (68KB padded, stride 136 = 16B-aligned + bank-uniform for b128), staged once per
// block; inner loop uses ds_read_b128 (lgkmcnt-batched, 12cyc throughput). A-frags direct
// from global into registers (R10 path). C stored straight to global (2B/lane stores, no
// C-stage LDS, no waits). One __syncthreads total. 68KB LDS -> 2 blocks/CU.
__global__ __launch_bounds__(256, 2) void k_gemm(const float* __restrict__ X,
                                                 const unsigned short* __restrict__ Wth,
                                                 const unsigned short* __restrict__ Wtl,
                                                 const float* __restrict__ scale,
                                                 unsigned short* __restrict__ out,
                                                 int nrows) {
    __shared__ __align__(16) unsigned short Wl[2][128 * WS];   // 68 KB (hi, lo)
    const int t = threadIdx.x;
    const int w = t >> 6;
    const int lane = t & 63;
    const int l15 = lane & 15;
    const int quad = lane >> 4;
    const int rbase = blockIdx.x * 64 + w * 16;   // wave's 16-row tile
    const int arow = rbase + l15;                 // this lane's A row
    const bool avalid = arow < nrows;

    // A: 8 float4 loads, issue immediately (independent of staging)
    float4 xa[4][2];
#pragma unroll
    for (int kc = 0; kc < 4; ++kc) {
        const float* src = X + (size_t)arow * TD + kc * 32 + quad * 8;
        xa[kc][0] = avalid ? *(const float4*)src       : make_float4(0.f, 0.f, 0.f, 0.f);
        xa[kc][1] = avalid ? *(const float4*)(src + 4) : make_float4(0.f, 0.f, 0.f, 0.f);
    }

    // stage W hi+lo -> padded LDS: 2048 uint4 per plane, 8 per thread
    {
        const uint4* gh = (const uint4*)Wth;
        const uint4* gl = (const uint4*)Wtl;
#pragma unroll
        for (int it = 0; it < 8; ++it) {
            int idx = t + it * 256;            // 0..2047
            int n = idx >> 4, kg = idx & 15;   // row n, k-group kg (8 bf16 each)
            uint4 vh = gh[idx];
            uint4 vl = gl[idx];
            *(uint4*)&Wl[0][n * WS + kg * 8] = vh;
            *(uint4*)&Wl[1][n * WS + kg * 8] = vl;
        }
    }

    // convert A to bf16 hi/lo fragments while staging is in flight
    bf16x8 ah[4], al[4];
#pragma unroll
    for (int kc = 0; kc < 4; ++kc) {
#pragma unroll
        for (int j = 0; j < 8; ++j) {
            float v = (j < 4) ? ((const float*)&xa[kc][0])[j] : ((const float*)&xa[kc][1])[j - 4];
            unsigned short h = f2bf(v);
            ah[kc][j] = (short)h;
            al[kc][j] = (short)f2bf(v - bf2f(h));
        }
    }
    __syncthreads();

    f32x4 acc[8];
#pragma unroll
    for (int b = 0; b < 8; ++b) acc[b] = (f32x4){0.f, 0.f, 0.f, 0.f};

#pragma unroll
    for (int kc = 0; kc < 4; ++kc) {
        const int koff = kc * 32 + quad * 8;
#pragma unroll
        for (int b = 0; b < 8; ++b) {
            const int boff = (b * 16 + l15) * WS + koff;
            bf16x8 bh = *(const bf16x8*)&Wl[0][boff];
            bf16x8 bl = *(const bf16x8*)&Wl[1][boff];
            acc[b] = __builtin_amdgcn_mfma_f32_16x16x32_bf16(ah[kc], bh, acc[b], 0, 0, 0);
            acc[b] = __builtin_amdgcn_mfma_f32_16x16x32_bf16(al[kc], bh, acc[b], 0, 0, 0);
            acc[b] = __builtin_amdgcn_mfma_f32_16x16x32_bf16(ah[kc], bl, acc[b], 0, 0, 0);
        }
    }

    // epilogue: C/D layout col=lane&15, row=quad*4+reg -> scale + direct bf16 global stores
    {
        int grow = rbase + quad * 4;              // multiple of 4; nrows % 4 == 0
        if (grow < nrows) {
            float4 s4 = *(const float4*)&scale[grow];
#pragma unroll
            for (int b = 0; b < 8; ++b) {
                int col = b * 16 + l15;
                out[(size_t)(grow + 0) * TD + col] = f2bf(acc[b][0] * s4.x);
                out[(size_t)(grow + 1) * TD + col] = f2bf(acc[b][1] * s4.y);
                out[(size_t)(grow + 2) * TD + col] = f2bf(acc[b][2] * s4.z);
                out[(size_t)(grow + 3) * TD + col] = f2bf(acc[b][3] * s4.w);
            }
        }
    }
}

// ---------------- CSR aggregation: bf16 gather, f64 accumulate (order-invariant), f32 out ----------------
__global__ __launch_bounds__(256) void k_agg(const unsigned short* __restrict__ hs, const int* __restrict__ rowptr,
                                             const int* __restrict__ esrc, const float* __restrict__ dinv,
                                             const float* __restrict__ bias, float* __restrict__ out,
                                             int n, int relu) {
    int node = blockIdx.x * 16 + (threadIdx.x >> 4);
    int lane = threadIdx.x & 15;
    if (node >= n) return;
    int s = rowptr[node], e = rowptr[node + 1];
    const uint4* h16 = (const uint4*)hs;
    double a0 = 0, a1 = 0, a2 = 0, a3 = 0, a4 = 0, a5 = 0, a6 = 0, a7 = 0;
    int i = s;
    for (; i + 2 <= e; i += 2) {
        uint4 u = h16[(size_t)esrc[i] * 16 + lane];
        uint4 v = h16[(size_t)esrc[i + 1] * 16 + lane];
        a0 += (double)__uint_as_float(u.x << 16); a1 += (double)__uint_as_float(u.x & 0xffff0000u);
        a2 += (double)__uint_as_float(u.y << 16); a3 += (double)__uint_as_float(u.y & 0xffff0000u);
        a4 += (double)__uint_as_float(u.z << 16); a5 += (double)__uint_as_float(u.z & 0xffff0000u);
        a6 += (double)__uint_as_float(u.w << 16); a7 += (double)__uint_as_float(u.w & 0xffff0000u);
        a0 += (double)__uint_as_float(v.x << 16); a1 += (double)__uint_as_float(v.x & 0xffff0000u);
        a2 += (double)__uint_as_float(v.y << 16); a3 += (double)__uint_as_float(v.y & 0xffff0000u);
        a4 += (double)__uint_as_float(v.z << 16); a5 += (double)__uint_as_float(v.z & 0xffff0000u);
        a6 += (double)__uint_as_float(v.w << 16); a7 += (double)__uint_as_float(v.w & 0xffff0000u);
    }
    if (i < e) {
        uint4 u = h16[(size_t)esrc[i] * 16 + lane];
        a0 += (double)__uint_as_float(u.x << 16); a1 += (double)__uint_as_float(u.x & 0xffff0000u);
        a2 += (double)__uint_as_float(u.y << 16); a3 += (double)__uint_as_float(u.y & 0xffff0000u);
        a4 += (double)__uint_as_float(u.z << 16); a5 += (double)__uint_as_float(u.z & 0xffff0000u);
        a6 += (double)__uint_as_float(u.w << 16); a7 += (double)__uint_as_float(u.w & 0xffff0000u);
    }
    double di = (double)dinv[node];
    float4 b0 = ((const float4*)bias)[lane * 2];
    float4 b1 = ((const float4*)bias)[lane * 2 + 1];
    float o0 = (float)(di * a0 + (double)b0.x);
    float o1 = (float)(di * a1 + (double)b0.y);
    float o2 = (float)(di * a2 + (double)b0.z);
    float o3 = (float)(di * a3 + (double)b0.w);
    float o4 = (float)(di * a4 + (double)b1.x);
    float o5 = (float)(di * a5 + (double)b1.y);
    float o6 = (float)(di * a6 + (double)b1.z);
    float o7 = (float)(di * a7 + (double)b1.w);
    if (relu) {
        o0 = fmaxf(o0, 0.f); o1 = fmaxf(o1, 0.f); o2 = fmaxf(o2, 0.f); o3 = fmaxf(o3, 0.f);
        o4 = fmaxf(o4, 0.f); o5 = fmaxf(o5, 0.f); o6 = fmaxf(o6, 0.f); o7 = fmaxf(o7, 0.f);
    }
    ((float4*)out)[(size_t)node * 32 + lane * 2]     = make_float4(o0, o1, o2, o3);
    ((float4*)out)[(size_t)node * 32 + lane * 2 + 1] = make_float4(o4, o5, o6, o7);
}

// ---------------- relation bucketing: block-aggregated histograms (16 global atomics/block) ----------------
__global__ __launch_bounds__(256) void k_rcnt(const int* __restrict__ rel, int* __restrict__ rcount, int es) {
    __shared__ int lh[16];
    int t = threadIdx.x;
    if (t < 16) lh[t] = 0;
    __syncthreads();
#pragma unroll
    for (int i = 0; i < 4; ++i) {
        int e = blockIdx.x * 1024 + i * 256 + t;
        if (e < es) atomicAdd(&lh[rel[e]], 1);
    }
    __syncthreads();
    if (t < 16 && lh[t]) atomicAdd(&rcount[t], lh[t]);
}

__global__ void k_roff(const int* __restrict__ rcount, int* __restrict__ roff,
                       int* __restrict__ chunkoff, int nr) {
    if (threadIdx.x == 0 && blockIdx.x == 0) {
        int run = 0, crun = 0;
        for (int r = 0; r < nr; ++r) {
            roff[r] = run; chunkoff[r] = crun;
            run += rcount[r]; crun += (rcount[r] + SC_T - 1) / SC_T;
        }
        roff[nr] = run; chunkoff[nr] = crun;
    }
}

__global__ __launch_bounds__(256) void k_bucket(const int* __restrict__ rel, int* __restrict__ cursor,
                                                int* __restrict__ eidx, int es) {
    __shared__ int lh[16];
    __shared__ int lbase[16];
    int t = threadIdx.x;
    if (t < 16) lh[t] = 0;
    __syncthreads();
    int r[4], lr[4];
#pragma unroll
    for (int i = 0; i < 4; ++i) {
        int e = blockIdx.x * 1024 + i * 256 + t;
        if (e < es) {
            r[i] = rel[e];
            lr[i] = atomicAdd(&lh[r[i]], 1);   // LDS atomic: intra-block rank
        } else r[i] = -1;
    }
    __syncthreads();
    if (t < 16) lbase[t] = lh[t] ? atomicAdd(&cursor[t], lh[t]) : 0;   // reserve range
    __syncthreads();
#pragma unroll
    for (int i = 0; i < 4; ++i)
        if (r[i] >= 0) eidx[lbase[r[i]] + lr[i]] = blockIdx.x * 1024 + i * 256 + t;
}

// ---------------- batched scoring: SC_T triples of ONE relation per block, W[r] staged once ----------------
__global__ __launch_bounds__(256) void k_score_r(const float* __restrict__ z, const float* __restrict__ relW,
                                                 const int* __restrict__ eidx, const int* __restrict__ head,
                                                 const int* __restrict__ tail, const int* __restrict__ roff,
                                                 const int* __restrict__ chunkoff, float* __restrict__ out,
                                                 int R_) {
    __shared__ __align__(16) float Wl[TD * TD];      // 64 KB
    __shared__ __align__(16) float zhL[SC_T * TD];   // 4 KB
    __shared__ __align__(16) float ztL[SC_T * TD];   // 4 KB
    __shared__ int eids[SC_T];
    __shared__ int co[17], ro[17];
    __shared__ float red[4][SC_T];
    const int t = threadIdx.x;
    const int b = blockIdx.x;
    if (t < 17 && t <= R_) { co[t] = chunkoff[t]; ro[t] = roff[t]; }
    __syncthreads();
    int r = 0;
    while (r < R_ && co[r + 1] <= b) ++r;
    if (r >= R_) return;                       // uniform: all threads exit together
    const int base = ro[r] + (b - co[r]) * SC_T;
    const int nt = min(SC_T, ro[r + 1] - base);
    if (t < SC_T) eids[t] = (t < nt) ? eidx[base + t] : -1;
    __syncthreads();
    {   // stage zh/zt: 256 float4, 1 per thread
        int tt = t >> 5, c4 = t & 31;
        float4 vh = make_float4(0.f, 0.f, 0.f, 0.f), vt = vh;
        int e = eids[tt];
        if (e >= 0) {
            vh = ((const float4*)(z + (size_t)head[e] * TD))[c4];
            vt = ((const float4*)(z + (size_t)tail[e] * TD))[c4];
        }
        ((float4*)(zhL + tt * TD))[c4] = vh;
        ((float4*)(ztL + tt * TD))[c4] = vt;
    }
    {   // stage W[r]: 4096 float4
        const float4* W4 = (const float4*)(relW + (size_t)r * TD * TD);
        float4* Wl4 = (float4*)Wl;
#pragma unroll
        for (int i = 0; i < 16; ++i) Wl4[t + i * 256] = W4[t + i * 256];
    }
    __syncthreads();

    const int c  = (t & 31) * 4;    // cols c..c+3
    const int i0 = (t >> 5) * 16;   // 16-row i segment
    float4 acc[SC_T];
#pragma unroll
    for (int u = 0; u < SC_T; ++u) acc[u] = make_float4(0.f, 0.f, 0.f, 0.f);
#pragma unroll 4
    for (int i = i0; i < i0 + 16; ++i) {
        float4 wv = *(const float4*)&Wl[i * TD + c];
#pragma unroll
        for (int u = 0; u < SC_T; ++u) {
            float h = zhL[u * TD + i];
            acc[u].x = fmaf(h, wv.x, acc[u].x);
            acc[u].y = fmaf(h, wv.y, acc[u].y);
            acc[u].z = fmaf(h, wv.z, acc[u].z);
            acc[u].w = fmaf(h, wv.w, acc[u].w);
        }
    }
    float pth[SC_T];
#pragma unroll
    for (int u = 0; u < SC_T; ++u) {
        float4 z4 = *(const float4*)&ztL[u * TD + c];
        pth[u] = acc[u].x * z4.x + acc[u].y * z4.y + acc[u].z * z4.z + acc[u].w * z4.w;
    }
#pragma unroll
    for (int off = 32; off > 0; off >>= 1)
#pragma unroll
        for (int u = 0; u < SC_T; ++u) pth[u] += __shfl_down(pth[u], off);
    if ((t & 63) == 0) {
        int wv = t >> 6;
#pragma unroll
        for (int u = 0; u < SC_T; ++u) red[wv][u] = pth[u];
    }
    __syncthreads();
    if (t < SC_T) {
        int e = eids[t];
        if (e >= 0) out[e] = red[0][t] + red[1][t] + red[2][t] + red[3][t];
    }
}

extern "C" void kernel_launch(void* const* d_in, const int* in_sizes, int n_in,
                              void* d_out, int out_size, void* d_ws, size_t ws_size,
                              hipStream_t stream) {
    const float* x0   = (const float*)d_in[0];
    const float* W1   = (const float*)d_in[1];
    const float* b1   = (const float*)d_in[2];
    const float* W2   = (const float*)d_in[3];
    const float* b2   = (const float*)d_in[4];
    const float* relW = (const float*)d_in[5];
    const int*   ei   = (const int*)d_in[6];
    const int*   rel  = (const int*)d_in[7];
    const int*   head = (const int*)d_in[8];
    const int*   tail = (const int*)d_in[9];
    float* outp = (float*)d_out;

    const int N_  = in_sizes[0] / TD;
    const int E_  = in_sizes[6] / 2;
    const int ES_ = in_sizes[7];
    const int R_  = in_sizes[5] / (TD * TD);
    const int nb  = (N_ + 1023) / 1024;
    const int ntiles64 = (N_ + 63) / 64;

    char* p = (char*)d_ws;
    auto alloc = [&](size_t bytes) { char* r = p; p += (bytes + 255) & ~(size_t)255; return r; };
    int*            deg    = (int*)           alloc((size_t)N_ * 4);
    float*          dinv   = (float*)         alloc((size_t)N_ * 4);
    int*            rowptr = (int*)           alloc(((size_t)N_ + 1) * 4);
    int*            bsums  = (int*)           alloc((size_t)nb * 4);
    int*            esrc   = (int*)           alloc((size_t)E_ * 4);
    unsigned short* Wt     = (unsigned short*)alloc((size_t)4 * 16384 * 2);   // W1h,W1l,W2h,W2l
    int*            rcount = (int*)           alloc((size_t)R_ * 4);
    int*            roff   = (int*)           alloc(((size_t)R_ + 1) * 4);
    int*            chkoff = (int*)           alloc(((size_t)R_ + 1) * 4);
    int*            cursor = (int*)           alloc((size_t)R_ * 4);
    int*            eidx   = (int*)           alloc((size_t)ES_ * 4);
    unsigned short* bufA   = (unsigned short*)alloc((size_t)N_ * TD * 2);     // bf16 h-scaled
    float*          bufB   = (float*)         alloc((size_t)N_ * TD * 4);     // f32 conv out
    int*            rank   = (int*)bufA;   // alias: dead before first k_gemm writes bufA (E*4 <= N*TD*2)

    hipMemsetAsync(deg, 0, (size_t)N_ * 4, stream);
    hipMemsetAsync(rcount, 0, (size_t)R_ * 4, stream);
    k_rank  <<<(E_ + 255) / 256, 256, 0, stream>>>(ei, deg, rank, E_);
    k_dinv  <<<(N_ + 255) / 256, 256, 0, stream>>>(deg, dinv, N_);
    k_scan1 <<<nb, 256, 0, stream>>>(deg, rowptr, bsums, N_);
    k_scan2 <<<1, 256, 0, stream>>>(bsums, nb, rowptr + N_);
    k_scan3 <<<(N_ + 255) / 256, 256, 0, stream>>>(rowptr, bsums, N_);
    k_place <<<(E_ + 255) / 256, 256, 0, stream>>>(ei, rowptr, rank, esrc, E_);
    k_wsplit<<<128, 256, 0, stream>>>(W1, W2, Wt);

    // relation bucketing for scoring (block-aggregated atomics)
    k_rcnt  <<<(ES_ + 1023) / 1024, 256, 0, stream>>>(rel, rcount, ES_);
    k_roff  <<<1, 64, 0, stream>>>(rcount, roff, chkoff, R_);
    hipMemcpyAsync(cursor, roff, (size_t)R_ * 4, hipMemcpyDeviceToDevice, stream);
    k_bucket<<<(ES_ + 1023) / 1024, 256, 0, stream>>>(rel, cursor, eidx, ES_);

    // conv1: bufA = bf16(dinv * (x0 @ W1)); bufB = relu(dinv*agg(bufA) + b1)
    k_gemm<<<ntiles64, 256, 0, stream>>>(x0, Wt, Wt + 16384, dinv, bufA, N_);
    k_agg <<<(N_ + 15) / 16, 256, 0, stream>>>(bufA, rowptr, esrc, dinv, b1, bufB, N_, 1);
    // conv2: bufA = bf16(dinv * (bufB @ W2)); bufB = dinv*agg(bufA) + b2  (= z)
    k_gemm<<<ntiles64, 256, 0, stream>>>(bufB, Wt + 32768, Wt + 49152, dinv, bufA, N_);
    k_agg <<<(N_ + 15) / 16, 256, 0, stream>>>(bufA, rowptr, esrc, dinv, b2, bufB, N_, 0);

    // scoring: blocks = chunks (upper bound ES/SC_T + R); out-of-range blocks exit via chunkoff
    k_score_r<<<(ES_ + SC_T - 1) / SC_T + R_, 256, 0, stream>>>(bufB, relW, eidx, head, tail,
                                                                roff, chkoff, outp, R_);
}